// Round 1
// baseline (642.881 us; speedup 1.0000x reference)
//
#include <hip/hip_runtime.h>

// EvolvedNet: 32-node graph relaxation, 128 edges applied sequentially per
// sweep, 32 sweeps, batched over 524288 independent elements.
//
// Strategy: one thread per batch element. Node state (32 f32) lives in LDS
// laid out [node][tid] so wave-uniform node index -> lane-consecutive banks
// (2-way aliasing, free). Edge data read via uniform (scalar) loads.
// tanh via exp2+rcp hardware ops.

#define N_NODES   32
#define N_INPUTS  8
#define N_OUTPUTS 4
#define N_EDGES   128
#define BATCH     524288
#define BLOCK     256

// 2 * log2(e)
#define TWO_LOG2E 2.88539008177792681472f

__device__ __forceinline__ float tanh_from_exp2(float x_times_k) {
    // expects x_times_k = x * 2*log2(e); tanh(x) = 1 - 2/(1+2^(x*2log2e))
    const float u = __builtin_amdgcn_exp2f(x_times_k);
    return 1.0f - 2.0f * __builtin_amdgcn_rcpf(1.0f + u);
}

__global__ __launch_bounds__(BLOCK)
void EvolvedNet_80032420593868_kernel(const float* __restrict__ x,
                                      const float* __restrict__ w,
                                      const int*   __restrict__ src,
                                      const int*   __restrict__ dst,
                                      float*       __restrict__ out) {
    // vals[node][tid]: per-thread column; node index uniform across the wave
    // -> address = node_off + tid*4 -> banks 0..31 twice across 64 lanes (free).
    __shared__ float vals[N_NODES][BLOCK];

    const int tid = threadIdx.x;
    const int b   = blockIdx.x * BLOCK + tid;

    // init: inputs into nodes 0..7, zeros elsewhere. Coalesced reads.
#pragma unroll
    for (int n = 0; n < N_INPUTS; ++n)
        vals[n][tid] = x[n * BATCH + b];
#pragma unroll
    for (int n = N_INPUTS; n < N_NODES; ++n)
        vals[n][tid] = 0.0f;

    // No __syncthreads needed anywhere: each thread touches only its own
    // column; within-thread LDS ops are ordered by the in-order DS pipe.

    for (int sweep = 0; sweep < N_NODES; ++sweep) {
        // Partial unroll: batches the uniform s_loads + gives ILP across
        // (usually independent) consecutive edges, without fully unrolling
        // (full unroll would let LICM hoist 384 scalar loads -> SGPR blowup).
#pragma unroll 8
        for (int e = 0; e < N_EDGES; ++e) {
            const int   s  = src[e];       // uniform -> s_load
            const int   d  = dst[e];       // uniform -> s_load
            const float wk = w[e] * TWO_LOG2E;
            const float v  = vals[s][tid];
            const float t  = tanh_from_exp2(v * wk);
            vals[d][tid] += t;             // sequential semantics preserved:
                                           // strict program order per thread
        }
    }

    // outputs: tanh(vals[28..31]); out is [N_OUTPUTS][BATCH] flat.
#pragma unroll
    for (int o = 0; o < N_OUTPUTS; ++o) {
        const float v = vals[N_NODES - N_OUTPUTS + o][tid];
        out[o * BATCH + b] = tanh_from_exp2(v * TWO_LOG2E);
    }
}

extern "C" void kernel_launch(void* const* d_in, const int* in_sizes, int n_in,
                              void* d_out, int out_size, void* d_ws, size_t ws_size,
                              hipStream_t stream) {
    const float* x   = (const float*)d_in[0];
    const float* w   = (const float*)d_in[1];
    const int*   src = (const int*)d_in[2];
    const int*   dst = (const int*)d_in[3];
    float*       out = (float*)d_out;

    const int grid = BATCH / BLOCK;  // 2048 blocks, exact
    EvolvedNet_80032420593868_kernel<<<grid, BLOCK, 0, stream>>>(x, w, src, dst, out);
}